// Round 8
// baseline (1081.622 us; speedup 1.0000x reference)
//
#include <hip/hip_runtime.h>

#define CH 64
#define NBUCK 1024        // buckets = dst >> 7 (128 nodes/bucket); needs N <= 131072
#define BSHIFT 7
#define BMASK 127
#define NBLK_P 128        // partition blocks; must match k_hist/k_partition/k_bucketscan

// ---- CSR-lite build: bucket sort only (no per-node permutation) -----------

__global__ __launch_bounds__(256) void k_hist(const int* __restrict__ dst,
                                              int* __restrict__ blkhist, int E) {
    __shared__ int h[NBUCK];
    for (int i = threadIdx.x; i < NBUCK; i += blockDim.x) h[i] = 0;
    __syncthreads();
    int chunk = (E + NBLK_P - 1) / NBLK_P;
    int beg = blockIdx.x * chunk;
    int end = min(beg + chunk, E);
    for (int e = beg + threadIdx.x; e < end; e += blockDim.x)
        atomicAdd(&h[dst[e] >> BSHIFT], 1);
    __syncthreads();
    for (int i = threadIdx.x; i < NBUCK; i += blockDim.x)
        blkhist[blockIdx.x * NBUCK + i] = h[i];
}

// One wave per bucket: scan blkhist[b][t] along b (128 values, 2/lane).
__global__ __launch_bounds__(256) void k_bucketscan(const int* __restrict__ blkhist,
                                                    int* __restrict__ off_t,
                                                    int* __restrict__ tot) {
    int lane = threadIdx.x & 63;
    int t = (blockIdx.x * blockDim.x + threadIdx.x) >> 6;   // bucket id 0..1023
    int b0 = lane * 2, b1 = b0 + 1;
    int v0 = blkhist[b0 * NBUCK + t];
    int v1 = blkhist[b1 * NBUCK + t];
    int ps = v0 + v1;
    int sc = ps;
#pragma unroll
    for (int o = 1; o < 64; o <<= 1) {
        int u = __shfl_up(sc, o, 64);
        if (lane >= o) sc += u;
    }
    int excl = sc - ps;
    off_t[t * NBLK_P + b0] = excl;
    off_t[t * NBLK_P + b1] = excl + v0;
    if (lane == 63) tot[t] = sc;
}

// Single small block: exclusive scan of 1024 bucket totals -> bbase.
__global__ __launch_bounds__(1024) void k_scantot(const int* __restrict__ tot,
                                                  int* __restrict__ bbase) {
    __shared__ int sh[NBUCK];
    int t = threadIdx.x;
    int v = tot[t];
    sh[t] = v;
    __syncthreads();
    for (int o = 1; o < NBUCK; o <<= 1) {
        int u = (t >= o) ? sh[t - o] : 0;
        __syncthreads();
        sh[t] += u;
        __syncthreads();
    }
    bbase[t] = sh[t] - v;
    if (t == NBUCK - 1) bbase[NBUCK] = sh[t];
}

__global__ __launch_bounds__(256) void k_partition(const int* __restrict__ src,
                                                   const int* __restrict__ dst,
                                                   const int* __restrict__ off_t,
                                                   const int* __restrict__ bbase,
                                                   unsigned int* __restrict__ ebuf, int E) {
    __shared__ int cur[NBUCK];
    for (int i = threadIdx.x; i < NBUCK; i += blockDim.x)
        cur[i] = bbase[i] + off_t[i * NBLK_P + blockIdx.x];
    __syncthreads();
    int chunk = (E + NBLK_P - 1) / NBLK_P;
    int beg = blockIdx.x * chunk;
    int end = min(beg + chunk, E);
    for (int e = beg + threadIdx.x; e < end; e += blockDim.x) {
        int s = src[e];
        int d = dst[e];
        int p = atomicAdd(&cur[d >> BSHIFT], 1);
        ebuf[p] = ((unsigned int)(d & BMASK) << 17) | (unsigned int)s;
    }
}

// ---- fused per-bucket: deg count -> dinv, then GEMM1 for the 128 nodes ----
// hs[node][c] = (x @ W1)[node][c] * dinv[node]

__global__ __launch_bounds__(256) void k_deg_gemm(const unsigned int* __restrict__ ebuf,
                                                  const int* __restrict__ bbase,
                                                  const float* __restrict__ x,
                                                  const float* __restrict__ W,
                                                  float* __restrict__ dinv,
                                                  float* __restrict__ hs, int n) {
    __shared__ float Ws[CH * CH];
    __shared__ int cnt[128];
    __shared__ float dl[128];
    int t = threadIdx.x;
    for (int i = t; i < CH * CH; i += 256) Ws[i] = W[i];
    if (t < 128) cnt[t] = 0;
    __syncthreads();
    int e0 = bbase[blockIdx.x], e1 = bbase[blockIdx.x + 1];
    for (int e = e0 + t; e < e1; e += 256)
        atomicAdd(&cnt[ebuf[e] >> 17], 1);
    __syncthreads();
    int kb = blockIdx.x << BSHIFT;
    if (t < 128) {
        float dv = rsqrtf((float)(cnt[t] + 1));   // +1 self-loop
        dl[t] = dv;
        if (kb + t < n) dinv[kb + t] = dv;
    }
    __syncthreads();
    int lane = t & 63;
    int w = t >> 6;
    for (int tt = w * 32; tt < w * 32 + 32; ++tt) {
        int node = kb + tt;
        if (node >= n) break;
        float v = x[(size_t)node * CH + lane];
        float acc = 0.0f;
#pragma unroll
        for (int kk = 0; kk < CH; ++kk)
            acc = fmaf(__shfl(v, kk, 64), Ws[kk * CH + lane], acc);
        hs[(size_t)node * CH + lane] = acc * dl[tt];
    }
}

// ---- per-bucket gather (LDS accumulate) + relu/bias + GEMM(W2) + Wl -> z --
// Edge stream: coalesced ebuf loads, per edge one 256B row load + ds_add_f32.
// No per-node col chains; high load duty cycle.

__global__ __launch_bounds__(256) void k_bgather(const unsigned int* __restrict__ ebuf,
                                                 const int* __restrict__ bbase,
                                                 const float* __restrict__ hs,
                                                 const float* __restrict__ dinv,
                                                 const float* __restrict__ W,
                                                 const float* __restrict__ bias,
                                                 const float* __restrict__ Wl,
                                                 float* __restrict__ z, int n) {
    __shared__ float agg[128 * CH];   // 32 KB
    __shared__ float Ws[CH * CH];     // 16 KB
    int t = threadIdx.x;
    for (int i = t; i < CH * CH; i += 256) Ws[i] = W[i];
    for (int i = t; i < 128 * CH; i += 256) agg[i] = 0.0f;
    __syncthreads();

    int lane = t & 63;
    int w    = t >> 6;
    int e0 = bbase[blockIdx.x], e1 = bbase[blockIdx.x + 1];

    for (int base = e0 + w * 64; base < e1; base += 256) {
        int m = e1 - base;
        if (m > 64) m = 64;
        unsigned int ew = (lane < m) ? ebuf[base + lane] : 0u;
        if (m == 64) {
#pragma unroll 8
            for (int j = 0; j < 64; ++j) {
                unsigned int u = __shfl(ew, j, 64);
                float a = hs[(size_t)(u & 0x1FFFFu) * CH + lane];
                atomicAdd(&agg[(u >> 17) * CH + lane], a);
            }
        } else {
            for (int j = 0; j < m; ++j) {
                unsigned int u = __shfl(ew, j, 64);
                float a = hs[(size_t)(u & 0x1FFFFu) * CH + lane];
                atomicAdd(&agg[(u >> 17) * CH + lane], a);
            }
        }
    }
    __syncthreads();

    float wl = Wl[lane];
    float bi = bias[lane];
    int kb = blockIdx.x << BSHIFT;
    for (int tt = w * 32; tt < w * 32 + 32; ++tt) {
        int node = kb + tt;
        if (node >= n) break;
        float acc = agg[tt * CH + lane] + hs[(size_t)node * CH + lane];  // + self
        float d = dinv[node];
        float v = fmaxf(fmaf(acc, d, bi), 0.0f);   // h1 = relu(agg1 + b1)
        float acc2 = 0.0f;
#pragma unroll
        for (int kk = 0; kk < CH; ++kk)
            acc2 = fmaf(__shfl(v, kk, 64), Ws[kk * CH + lane], acc2);
        float p = acc2 * d * wl;                   // z = (h2*dinv) . Wl
#pragma unroll
        for (int o = 32; o > 0; o >>= 1) p += __shfl_xor(p, o, 64);
        if (lane == 0) z[node] = p;
    }
}

// ---- per-bucket head: out[n] = sigmoid(dinv[n]*(z[n]+sum z[s]) + c0) ------

__global__ __launch_bounds__(256) void k_bhead(const unsigned int* __restrict__ ebuf,
                                               const int* __restrict__ bbase,
                                               const float* __restrict__ z,
                                               const float* __restrict__ dinv,
                                               const float* __restrict__ b2,
                                               const float* __restrict__ Wl,
                                               const float* __restrict__ bl,
                                               float* __restrict__ out, int n) {
    __shared__ float zagg[128];
    int t = threadIdx.x;
    int lane = t & 63;
    if (t < 128) zagg[t] = 0.0f;
    float c0 = b2[lane] * Wl[lane];
#pragma unroll
    for (int o = 32; o > 0; o >>= 1) c0 += __shfl_xor(c0, o, 64);
    c0 += bl[0];
    __syncthreads();
    int e0 = bbase[blockIdx.x], e1 = bbase[blockIdx.x + 1];
    for (int e = e0 + t; e < e1; e += 256) {
        unsigned int u = ebuf[e];
        atomicAdd(&zagg[u >> 17], z[u & 0x1FFFFu]);
    }
    __syncthreads();
    if (t < 128) {
        int node = (blockIdx.x << BSHIFT) + t;
        if (node < n) {
            float v = dinv[node] * (zagg[t] + z[node]) + c0;
            out[node] = 1.0f / (1.0f + expf(-v));
        }
    }
}

// ---- launch ---------------------------------------------------------------

extern "C" void kernel_launch(void* const* d_in, const int* in_sizes, int n_in,
                              void* d_out, int out_size, void* d_ws, size_t ws_size,
                              hipStream_t stream) {
    const float* x   = (const float*)d_in[0];
    const int*   ei  = (const int*)d_in[1];   // [2, E] row-major
    const float* W1  = (const float*)d_in[2];
    const float* b1  = (const float*)d_in[3];
    const float* W2  = (const float*)d_in[4];
    const float* b2  = (const float*)d_in[5];
    const float* Wl  = (const float*)d_in[6];
    const float* bl  = (const float*)d_in[7];
    float*       out = (float*)d_out;

    const int N = in_sizes[0] / CH;
    const int E = in_sizes[1] / 2;
    const int* src = ei;
    const int* dst = ei + E;

    const size_t Npad = ((size_t)N + 511) & ~(size_t)511;
    const size_t Epad = ((size_t)E + 511) & ~(size_t)511;

    float* A       = (float*)d_ws;                    // N*CH  (hs1)
    float* z       = A + (size_t)N * CH;              // N
    float* dinv    = z + Npad;                        // N
    unsigned int* ebuf = (unsigned int*)(dinv + Npad);// E
    int*   blkhist = (int*)(ebuf + Epad);             // NBLK_P*NBUCK
    int*   off_t   = blkhist + NBLK_P * NBUCK;        // NBUCK*NBLK_P (transposed)
    int*   bbase   = off_t + NBLK_P * NBUCK;          // NBUCK+1
    int*   tot     = bbase + NBUCK + 64;              // NBUCK

    const int TB = 256;
    const int NB_USED = (N + BMASK) >> BSHIFT;        // 782 buckets hold nodes

    // Bucket sort (scatter-free)
    k_hist<<<NBLK_P, TB, 0, stream>>>(dst, blkhist, E);
    k_bucketscan<<<NBUCK * 64 / TB, TB, 0, stream>>>(blkhist, off_t, tot);
    k_scantot<<<1, NBUCK, 0, stream>>>(tot, bbase);
    k_partition<<<NBLK_P, TB, 0, stream>>>(src, dst, off_t, bbase, ebuf, E);

    // Per-bucket: deg -> dinv, GEMM1 -> hs
    k_deg_gemm<<<NB_USED, TB, 0, stream>>>(ebuf, bbase, x, W1, dinv, A, N);

    // Per-bucket: LDS gather + relu/bias + GEMM2 + Wl-dot -> z
    k_bgather<<<NB_USED, TB, 0, stream>>>(ebuf, bbase, A, dinv, W2, b1, Wl, z, N);

    // Per-bucket head: scalar z gather + sigmoid
    k_bhead<<<NB_USED, TB, 0, stream>>>(ebuf, bbase, z, dinv, b2, Wl, bl, out, N);
}

// Round 9
// 363.543 us; speedup vs baseline: 2.9752x; 2.9752x over previous
//
#include <hip/hip_runtime.h>
#include <hip/hip_fp16.h>

#define CH 64
#define NBUCK 1024        // buckets = dst >> 7 (128 nodes/bucket); needs N <= 131072
#define BSHIFT 7
#define BMASK 127
#define NBLK_P 128        // partition blocks; must match k_hist/k_partition/k_bucketscan

// ---- CSR build: scatter-free two-level bucket sort ------------------------

__global__ __launch_bounds__(256) void k_hist(const int* __restrict__ dst,
                                              int* __restrict__ blkhist, int E) {
    __shared__ int h[NBUCK];
    for (int i = threadIdx.x; i < NBUCK; i += blockDim.x) h[i] = 0;
    __syncthreads();
    int chunk = (E + NBLK_P - 1) / NBLK_P;
    int beg = blockIdx.x * chunk;
    int end = min(beg + chunk, E);
    for (int e = beg + threadIdx.x; e < end; e += blockDim.x)
        atomicAdd(&h[dst[e] >> BSHIFT], 1);
    __syncthreads();
    for (int i = threadIdx.x; i < NBUCK; i += blockDim.x)
        blkhist[blockIdx.x * NBUCK + i] = h[i];
}

// One wave per bucket: scan blkhist[b][t] along b (128 values, 2/lane).
__global__ __launch_bounds__(256) void k_bucketscan(const int* __restrict__ blkhist,
                                                    int* __restrict__ off_t,
                                                    int* __restrict__ tot) {
    int lane = threadIdx.x & 63;
    int t = (blockIdx.x * blockDim.x + threadIdx.x) >> 6;   // bucket id 0..1023
    int b0 = lane * 2, b1 = b0 + 1;
    int v0 = blkhist[b0 * NBUCK + t];
    int v1 = blkhist[b1 * NBUCK + t];
    int ps = v0 + v1;
    int sc = ps;
#pragma unroll
    for (int o = 1; o < 64; o <<= 1) {
        int u = __shfl_up(sc, o, 64);
        if (lane >= o) sc += u;
    }
    int excl = sc - ps;
    off_t[t * NBLK_P + b0] = excl;
    off_t[t * NBLK_P + b1] = excl + v0;
    if (lane == 63) tot[t] = sc;
}

// Single small block: exclusive scan of 1024 bucket totals -> bbase.
__global__ __launch_bounds__(1024) void k_scantot(const int* __restrict__ tot,
                                                  int* __restrict__ bbase,
                                                  int* __restrict__ row_ptr, int n) {
    __shared__ int sh[NBUCK];
    int t = threadIdx.x;
    int v = tot[t];
    sh[t] = v;
    __syncthreads();
    for (int o = 1; o < NBUCK; o <<= 1) {
        int u = (t >= o) ? sh[t - o] : 0;
        __syncthreads();
        sh[t] += u;
        __syncthreads();
    }
    bbase[t] = sh[t] - v;
    if (t == NBUCK - 1) {
        bbase[NBUCK] = sh[t];
        row_ptr[n]   = sh[t];
    }
}

__global__ __launch_bounds__(256) void k_partition(const int* __restrict__ src,
                                                   const int* __restrict__ dst,
                                                   const int* __restrict__ off_t,
                                                   const int* __restrict__ bbase,
                                                   unsigned int* __restrict__ ebuf, int E) {
    __shared__ int cur[NBUCK];
    for (int i = threadIdx.x; i < NBUCK; i += blockDim.x)
        cur[i] = bbase[i] + off_t[i * NBLK_P + blockIdx.x];
    __syncthreads();
    int chunk = (E + NBLK_P - 1) / NBLK_P;
    int beg = blockIdx.x * chunk;
    int end = min(beg + chunk, E);
    for (int e = beg + threadIdx.x; e < end; e += blockDim.x) {
        int s = src[e];
        int d = dst[e];
        int p = atomicAdd(&cur[d >> BSHIFT], 1);
        ebuf[p] = ((unsigned int)(d & BMASK) << 17) | (unsigned int)s;
    }
}

__global__ __launch_bounds__(128) void k_bucket_csr(const unsigned int* __restrict__ ebuf,
                                                    const int* __restrict__ bbase,
                                                    int* __restrict__ row_ptr,
                                                    float* __restrict__ dinv,
                                                    int* __restrict__ col, int n) {
    __shared__ int cnt[128];
    __shared__ int cur[128];
    __shared__ int sc[128];
    int t = threadIdx.x;
    int k = blockIdx.x;
    int e0 = bbase[k], e1 = bbase[k + 1];
    cnt[t] = 0;
    __syncthreads();
    for (int e = e0 + t; e < e1; e += 128)
        atomicAdd(&cnt[ebuf[e] >> 17], 1);
    __syncthreads();
    int c = cnt[t];
    sc[t] = c;
    __syncthreads();
    for (int o = 1; o < 128; o <<= 1) {
        int v = (t >= o) ? sc[t - o] : 0;
        __syncthreads();
        sc[t] += v;
        __syncthreads();
    }
    int excl = sc[t] - c;
    int node = (k << BSHIFT) + t;
    if (node < n) {
        row_ptr[node] = e0 + excl;
        dinv[node] = rsqrtf((float)(c + 1));   // +1 self-loop
    }
    cur[t] = e0 + excl;
    __syncthreads();
    for (int e = e0 + t; e < e1; e += 128) {
        unsigned int u = ebuf[e];
        int p = atomicAdd(&cur[u >> 17], 1);
        col[p] = (int)(u & 0x1FFFFu);
    }
}

// ---- GEMM: wave-per-node, W in LDS, x-row broadcast via shuffle -----------
// Writes hs[node][c] = (x @ W1)[node][c] * dinv[node]  as fp16.

__global__ __launch_bounds__(256) void k_gemm64(const float* __restrict__ in,
                                                const float* __restrict__ W,
                                                const float* __restrict__ dinv,
                                                __half* __restrict__ hs, int n) {
    __shared__ float Ws[CH * CH];
    for (int i = threadIdx.x; i < CH * CH; i += blockDim.x) Ws[i] = W[i];
    __syncthreads();

    int lane = threadIdx.x & 63;
    int wid  = (blockIdx.x * blockDim.x + threadIdx.x) >> 6;
    int nw   = (gridDim.x * blockDim.x) >> 6;

    for (int node = wid; node < n; node += nw) {
        float v = in[(size_t)node * CH + lane];
        float acc = 0.0f;
#pragma unroll
        for (int k = 0; k < CH; ++k)
            acc = fmaf(__shfl(v, k, 64), Ws[k * CH + lane], acc);
        hs[(size_t)node * CH + lane] = __float2half(acc * dinv[node]);
    }
}

// ---- fused: gather(agg1) + bias + relu + GEMM(W2) + dot(Wl) -> z ----------
// Wave-per-node, wave-uniform scalar col loads, 8-deep independent row-load
// unroll. hs rows are fp16 (128 B/row): half the lines, half the miss bytes.
// Accumulation in fp32.

__global__ __launch_bounds__(256) void k_gather_gemm(const int* __restrict__ row_ptr,
                                                     const int* __restrict__ col,
                                                     const __half* __restrict__ hs,
                                                     const float* __restrict__ dinv,
                                                     const float* __restrict__ W,
                                                     const float* __restrict__ bias,
                                                     const float* __restrict__ Wl,
                                                     float* __restrict__ z, int n) {
    __shared__ float Ws[CH * CH];
    for (int i = threadIdx.x; i < CH * CH; i += blockDim.x) Ws[i] = W[i];
    __syncthreads();

    int lane = threadIdx.x & 63;
    int wid  = (blockIdx.x * blockDim.x + threadIdx.x) >> 6;
    int nw   = (gridDim.x * blockDim.x) >> 6;
    float wl = Wl[lane];
    float bi = bias[lane];

    for (int node = wid; node < n; node += nw) {
        int beg = row_ptr[node];
        int end = row_ptr[node + 1];
        float acc = __half2float(hs[(size_t)node * CH + lane]);  // self-loop

        int e = beg;
        for (; e + 8 <= end; e += 8) {             // 8 independent 128B row loads
            int s0 = col[e + 0], s1 = col[e + 1], s2 = col[e + 2], s3 = col[e + 3];
            int s4 = col[e + 4], s5 = col[e + 5], s6 = col[e + 6], s7 = col[e + 7];
            __half a0 = hs[(size_t)s0 * CH + lane];
            __half a1 = hs[(size_t)s1 * CH + lane];
            __half a2 = hs[(size_t)s2 * CH + lane];
            __half a3 = hs[(size_t)s3 * CH + lane];
            __half a4 = hs[(size_t)s4 * CH + lane];
            __half a5 = hs[(size_t)s5 * CH + lane];
            __half a6 = hs[(size_t)s6 * CH + lane];
            __half a7 = hs[(size_t)s7 * CH + lane];
            acc += __half2float(a0); acc += __half2float(a1);
            acc += __half2float(a2); acc += __half2float(a3);
            acc += __half2float(a4); acc += __half2float(a5);
            acc += __half2float(a6); acc += __half2float(a7);
        }
        for (; e < end; ++e)
            acc += __half2float(hs[(size_t)col[e] * CH + lane]);

        float d = dinv[node];
        float v = fmaxf(fmaf(acc, d, bi), 0.0f);   // h1 row = relu(agg1 + b1)
        float acc2 = 0.0f;
#pragma unroll
        for (int k = 0; k < CH; ++k)
            acc2 = fmaf(__shfl(v, k, 64), Ws[k * CH + lane], acc2);
        // z = (acc2 * d) . Wl   (wave reduction)
        float p = acc2 * d * wl;
#pragma unroll
        for (int o = 32; o > 0; o >>= 1) p += __shfl_xor(p, o, 64);
        if (lane == 0) z[node] = p;
    }
}

// ---- head: out[n] = sigmoid(dinv[n]*(z[n]+sum z[s]) + (b2.Wl + bl)) -------

__global__ __launch_bounds__(256) void k_head(const int* __restrict__ row_ptr,
                                              const int* __restrict__ col,
                                              const float* __restrict__ z,
                                              const float* __restrict__ dinv,
                                              const float* __restrict__ b2,
                                              const float* __restrict__ Wl,
                                              const float* __restrict__ bl,
                                              float* __restrict__ out, int n) {
    int lane = threadIdx.x & 63;
    float c0 = b2[lane] * Wl[lane];
#pragma unroll
    for (int o = 32; o > 0; o >>= 1) c0 += __shfl_xor(c0, o, 64);
    c0 += bl[0];

    int tid = blockIdx.x * blockDim.x + threadIdx.x;
    int st  = gridDim.x * blockDim.x;
    for (int node = tid; node < n; node += st) {
        int beg = row_ptr[node];
        int end = row_ptr[node + 1];
        float s = z[node];
        int e = beg;
        for (; e + 4 <= end; e += 4) {
            float t0 = z[col[e]];
            float t1 = z[col[e + 1]];
            float t2 = z[col[e + 2]];
            float t3 = z[col[e + 3]];
            s += t0; s += t1; s += t2; s += t3;
        }
        for (; e < end; ++e) s += z[col[e]];
        float v = dinv[node] * s + c0;
        out[node] = 1.0f / (1.0f + expf(-v));
    }
}

// ---- launch ---------------------------------------------------------------

extern "C" void kernel_launch(void* const* d_in, const int* in_sizes, int n_in,
                              void* d_out, int out_size, void* d_ws, size_t ws_size,
                              hipStream_t stream) {
    const float* x   = (const float*)d_in[0];
    const int*   ei  = (const int*)d_in[1];   // [2, E] row-major
    const float* W1  = (const float*)d_in[2];
    const float* b1  = (const float*)d_in[3];
    const float* W2  = (const float*)d_in[4];
    const float* b2  = (const float*)d_in[5];
    const float* Wl  = (const float*)d_in[6];
    const float* bl  = (const float*)d_in[7];
    float*       out = (float*)d_out;

    const int N = in_sizes[0] / CH;
    const int E = in_sizes[1] / 2;
    const int* src = ei;
    const int* dst = ei + E;

    const size_t Npad = ((size_t)N + 511) & ~(size_t)511;
    const size_t Epad = ((size_t)E + 511) & ~(size_t)511;

    __half* A      = (__half*)d_ws;                   // N*CH halves (hs1, fp16)
    float* z       = (float*)(A + (size_t)N * CH);    // N
    float* dinv    = z + Npad;                        // N
    int*   row_ptr = (int*)(dinv + Npad);             // N+1
    int*   col     = row_ptr + Npad;                  // E
    unsigned int* ebuf = (unsigned int*)(col + Epad); // E
    int*   blkhist = (int*)(ebuf + Epad);             // NBLK_P*NBUCK
    int*   off_t   = blkhist + NBLK_P * NBUCK;        // NBUCK*NBLK_P (transposed)
    int*   bbase   = off_t + NBLK_P * NBUCK;          // NBUCK+1
    int*   tot     = bbase + NBUCK + 64;              // NBUCK

    const int TB = 256;
    const int GRID = 2048;
    const int NB_USED = (N + BMASK) >> BSHIFT;

    // CSR build — scatter-free, no single-block serial stages
    k_hist<<<NBLK_P, TB, 0, stream>>>(dst, blkhist, E);
    k_bucketscan<<<NBUCK * 64 / TB, TB, 0, stream>>>(blkhist, off_t, tot);
    k_scantot<<<1, NBUCK, 0, stream>>>(tot, bbase, row_ptr, N);
    k_partition<<<NBLK_P, TB, 0, stream>>>(src, dst, off_t, bbase, ebuf, E);
    k_bucket_csr<<<NB_USED, 128, 0, stream>>>(ebuf, bbase, row_ptr, dinv, col, N);

    // Layer 1: A = (x @ W1) * dinv  (fp16)
    k_gemm64<<<GRID, TB, 0, stream>>>(x, W1, dinv, A, N);

    // Layer 2 fused: gather(A) -> relu(agg1+b1) @ W2 * dinv -> dot(Wl) -> z
    k_gather_gemm<<<GRID, TB, 0, stream>>>(row_ptr, col, A, dinv, W2, b1, Wl, z, N);

    // Head: scalar gather over z + sigmoid
    k_head<<<(N + TB - 1) / TB, TB, 0, stream>>>(row_ptr, col, z, dinv, b2, Wl, bl, out, N);
}

// Round 10
// 352.850 us; speedup vs baseline: 3.0654x; 1.0303x over previous
//
#include <hip/hip_runtime.h>
#include <hip/hip_fp16.h>

#define CH 64
#define NBUCK 1024        // buckets = dst >> 7 (128 nodes/bucket); needs N <= 131072
#define BSHIFT 7
#define BMASK 127
#define NBLK_P 128        // partition blocks; must match k_hist/k_partition/k_bucketscan

// ---- CSR build: scatter-free two-level bucket sort ------------------------

__global__ __launch_bounds__(256) void k_hist(const int* __restrict__ dst,
                                              int* __restrict__ blkhist, int E) {
    __shared__ int h[NBUCK];
    for (int i = threadIdx.x; i < NBUCK; i += blockDim.x) h[i] = 0;
    __syncthreads();
    int chunk = (E + NBLK_P - 1) / NBLK_P;
    int beg = blockIdx.x * chunk;
    int end = min(beg + chunk, E);
    for (int e = beg + threadIdx.x; e < end; e += blockDim.x)
        atomicAdd(&h[dst[e] >> BSHIFT], 1);
    __syncthreads();
    for (int i = threadIdx.x; i < NBUCK; i += blockDim.x)
        blkhist[blockIdx.x * NBUCK + i] = h[i];
}

// One wave per bucket: scan blkhist[b][t] along b (128 values, 2/lane).
__global__ __launch_bounds__(256) void k_bucketscan(const int* __restrict__ blkhist,
                                                    int* __restrict__ off_t,
                                                    int* __restrict__ tot) {
    int lane = threadIdx.x & 63;
    int t = (blockIdx.x * blockDim.x + threadIdx.x) >> 6;   // bucket id 0..1023
    int b0 = lane * 2, b1 = b0 + 1;
    int v0 = blkhist[b0 * NBUCK + t];
    int v1 = blkhist[b1 * NBUCK + t];
    int ps = v0 + v1;
    int sc = ps;
#pragma unroll
    for (int o = 1; o < 64; o <<= 1) {
        int u = __shfl_up(sc, o, 64);
        if (lane >= o) sc += u;
    }
    int excl = sc - ps;
    off_t[t * NBLK_P + b0] = excl;
    off_t[t * NBLK_P + b1] = excl + v0;
    if (lane == 63) tot[t] = sc;
}

// Single small block: exclusive scan of 1024 bucket totals -> bbase.
__global__ __launch_bounds__(1024) void k_scantot(const int* __restrict__ tot,
                                                  int* __restrict__ bbase,
                                                  int* __restrict__ row_ptr, int n) {
    __shared__ int sh[NBUCK];
    int t = threadIdx.x;
    int v = tot[t];
    sh[t] = v;
    __syncthreads();
    for (int o = 1; o < NBUCK; o <<= 1) {
        int u = (t >= o) ? sh[t - o] : 0;
        __syncthreads();
        sh[t] += u;
        __syncthreads();
    }
    bbase[t] = sh[t] - v;
    if (t == NBUCK - 1) {
        bbase[NBUCK] = sh[t];
        row_ptr[n]   = sh[t];
    }
}

__global__ __launch_bounds__(256) void k_partition(const int* __restrict__ src,
                                                   const int* __restrict__ dst,
                                                   const int* __restrict__ off_t,
                                                   const int* __restrict__ bbase,
                                                   unsigned int* __restrict__ ebuf, int E) {
    __shared__ int cur[NBUCK];
    for (int i = threadIdx.x; i < NBUCK; i += blockDim.x)
        cur[i] = bbase[i] + off_t[i * NBLK_P + blockIdx.x];
    __syncthreads();
    int chunk = (E + NBLK_P - 1) / NBLK_P;
    int beg = blockIdx.x * chunk;
    int end = min(beg + chunk, E);
    for (int e = beg + threadIdx.x; e < end; e += blockDim.x) {
        int s = src[e];
        int d = dst[e];
        int p = atomicAdd(&cur[d >> BSHIFT], 1);
        ebuf[p] = ((unsigned int)(d & BMASK) << 17) | (unsigned int)s;
    }
}

__global__ __launch_bounds__(128) void k_bucket_csr(const unsigned int* __restrict__ ebuf,
                                                    const int* __restrict__ bbase,
                                                    int* __restrict__ row_ptr,
                                                    float* __restrict__ dinv,
                                                    int* __restrict__ col, int n) {
    __shared__ int cnt[128];
    __shared__ int cur[128];
    __shared__ int sc[128];
    int t = threadIdx.x;
    int k = blockIdx.x;
    int e0 = bbase[k], e1 = bbase[k + 1];
    cnt[t] = 0;
    __syncthreads();
    for (int e = e0 + t; e < e1; e += 128)
        atomicAdd(&cnt[ebuf[e] >> 17], 1);
    __syncthreads();
    int c = cnt[t];
    sc[t] = c;
    __syncthreads();
    for (int o = 1; o < 128; o <<= 1) {
        int v = (t >= o) ? sc[t - o] : 0;
        __syncthreads();
        sc[t] += v;
        __syncthreads();
    }
    int excl = sc[t] - c;
    int node = (k << BSHIFT) + t;
    if (node < n) {
        row_ptr[node] = e0 + excl;
        dinv[node] = rsqrtf((float)(c + 1));   // +1 self-loop
    }
    cur[t] = e0 + excl;
    __syncthreads();
    for (int e = e0 + t; e < e1; e += 128) {
        unsigned int u = ebuf[e];
        int p = atomicAdd(&cur[u >> 17], 1);
        col[p] = (int)(u & 0x1FFFFu);
    }
}

// ---- GEMM: wave-per-node, W in LDS, x-row broadcast via shuffle -----------
// Writes hs[node][c] = (x @ W1)[node][c] * dinv[node]  as fp16.

__global__ __launch_bounds__(256) void k_gemm64(const float* __restrict__ in,
                                                const float* __restrict__ W,
                                                const float* __restrict__ dinv,
                                                __half* __restrict__ hs, int n) {
    __shared__ float Ws[CH * CH];
    for (int i = threadIdx.x; i < CH * CH; i += blockDim.x) Ws[i] = W[i];
    __syncthreads();

    int lane = threadIdx.x & 63;
    int wid  = (blockIdx.x * blockDim.x + threadIdx.x) >> 6;
    int nw   = (gridDim.x * blockDim.x) >> 6;

    for (int node = wid; node < n; node += nw) {
        float v = in[(size_t)node * CH + lane];
        float acc = 0.0f;
#pragma unroll
        for (int k = 0; k < CH; ++k)
            acc = fmaf(__shfl(v, k, 64), Ws[k * CH + lane], acc);
        hs[(size_t)node * CH + lane] = __float2half(acc * dinv[node]);
    }
}

// ---- fused: gather(agg1) + bias + relu + GEMM(W2) + dot(Wl) -> z ----------
// Paired-row fp16 gather: lane holds half2 (channels 2l,2l+1); lanes 0-31
// carry neighbor row e, lanes 32-63 row e+1 -> ONE load instruction fetches
// TWO rows. 8-deep unroll = 16 rows (= avg degree) in flight per wave.
// Epilogue split-k: each half-wave does 32 of the 64 k-steps, then one
// shfl_xor(32) combine -> serial chain halved.

__global__ __launch_bounds__(256) void k_gather_gemm(const int* __restrict__ row_ptr,
                                                     const int* __restrict__ col,
                                                     const __half2* __restrict__ hs2,
                                                     const float* __restrict__ dinv,
                                                     const float* __restrict__ W,
                                                     const float* __restrict__ bias,
                                                     const float* __restrict__ Wl,
                                                     float* __restrict__ z, int n) {
    __shared__ float Ws[CH * CH];
    for (int i = threadIdx.x; i < CH * CH; i += blockDim.x) Ws[i] = W[i];
    __syncthreads();
    const float2* Ws2 = (const float2*)Ws;

    int lane = threadIdx.x & 63;
    int l    = lane & 31;          // channel-pair index: channels 2l, 2l+1
    int g    = lane >> 5;          // half-wave: row parity
    int wid  = (blockIdx.x * blockDim.x + threadIdx.x) >> 6;
    int nw   = (gridDim.x * blockDim.x) >> 6;

    float2 wl2 = *(const float2*)(Wl + 2 * l);
    float2 bi2 = *(const float2*)(bias + 2 * l);

    for (int node = wid; node < n; node += nw) {
        int beg = row_ptr[node];
        int deg = row_ptr[node + 1] - beg;
        float2 acc = make_float2(0.f, 0.f);

        int e = 0;
        for (; e + 16 <= deg; e += 16) {       // 16 rows per batch, 8 load instrs
            int s0  = col[beg + e + 0],  s1  = col[beg + e + 1];
            int s2  = col[beg + e + 2],  s3  = col[beg + e + 3];
            int s4  = col[beg + e + 4],  s5  = col[beg + e + 5];
            int s6  = col[beg + e + 6],  s7  = col[beg + e + 7];
            int s8  = col[beg + e + 8],  s9  = col[beg + e + 9];
            int s10 = col[beg + e + 10], s11 = col[beg + e + 11];
            int s12 = col[beg + e + 12], s13 = col[beg + e + 13];
            int s14 = col[beg + e + 14], s15 = col[beg + e + 15];
            int i0 = g ? s1  : s0;
            int i1 = g ? s3  : s2;
            int i2 = g ? s5  : s4;
            int i3 = g ? s7  : s6;
            int i4 = g ? s9  : s8;
            int i5 = g ? s11 : s10;
            int i6 = g ? s13 : s12;
            int i7 = g ? s15 : s14;
            __half2 a0 = hs2[(size_t)i0 * 32 + l];
            __half2 a1 = hs2[(size_t)i1 * 32 + l];
            __half2 a2 = hs2[(size_t)i2 * 32 + l];
            __half2 a3 = hs2[(size_t)i3 * 32 + l];
            __half2 a4 = hs2[(size_t)i4 * 32 + l];
            __half2 a5 = hs2[(size_t)i5 * 32 + l];
            __half2 a6 = hs2[(size_t)i6 * 32 + l];
            __half2 a7 = hs2[(size_t)i7 * 32 + l];
            float2 f0 = __half22float2(a0), f1 = __half22float2(a1);
            float2 f2 = __half22float2(a2), f3 = __half22float2(a3);
            float2 f4 = __half22float2(a4), f5 = __half22float2(a5);
            float2 f6 = __half22float2(a6), f7 = __half22float2(a7);
            acc.x += f0.x + f1.x + f2.x + f3.x + f4.x + f5.x + f6.x + f7.x;
            acc.y += f0.y + f1.y + f2.y + f3.y + f4.y + f5.y + f6.y + f7.y;
        }
        for (; e + 2 <= deg; e += 2) {         // pair tail
            int s0 = col[beg + e], s1 = col[beg + e + 1];
            int i = g ? s1 : s0;
            float2 f = __half22float2(hs2[(size_t)i * 32 + l]);
            acc.x += f.x; acc.y += f.y;
        }
        if (g == 0) {                          // odd leftover + self-loop: half g=0 only
            if (e < deg) {
                float2 f = __half22float2(hs2[(size_t)col[beg + e] * 32 + l]);
                acc.x += f.x; acc.y += f.y;
            }
            float2 f = __half22float2(hs2[(size_t)node * 32 + l]);
            acc.x += f.x; acc.y += f.y;
        }
        // combine the two half-wave partial sums
        acc.x += __shfl_xor(acc.x, 32, 64);
        acc.y += __shfl_xor(acc.y, 32, 64);

        float d = dinv[node];
        float2 v;
        v.x = fmaxf(fmaf(acc.x, d, bi2.x), 0.0f);
        v.y = fmaxf(fmaf(acc.y, d, bi2.y), 0.0f);

        // acc2[c], c=2l,2l+1: half g sums k in [32g, 32g+32)
        float2 acc2 = make_float2(0.f, 0.f);
#pragma unroll
        for (int j = 0; j < 16; ++j) {
            int m = 16 * g + j;                // source lane holding k=2m, 2m+1
            float vx = __shfl(v.x, m, 64);
            float vy = __shfl(v.y, m, 64);
            float2 w0 = Ws2[(size_t)(2 * m + 0) * 32 + l];
            float2 w1 = Ws2[(size_t)(2 * m + 1) * 32 + l];
            acc2.x = fmaf(vx, w0.x, acc2.x); acc2.y = fmaf(vx, w0.y, acc2.y);
            acc2.x = fmaf(vy, w1.x, acc2.x); acc2.y = fmaf(vy, w1.y, acc2.y);
        }
        acc2.x += __shfl_xor(acc2.x, 32, 64);
        acc2.y += __shfl_xor(acc2.y, 32, 64);

        // z = d * (acc2 . Wl); lanes duplicated across halves -> reduce 32
        float p = (acc2.x * wl2.x + acc2.y * wl2.y) * d;
#pragma unroll
        for (int o = 16; o > 0; o >>= 1) p += __shfl_xor(p, o, 64);
        if (lane == 0) z[node] = p;
    }
}

// ---- head: out[n] = sigmoid(dinv[n]*(z[n]+sum z[s]) + (b2.Wl + bl)) -------

__global__ __launch_bounds__(256) void k_head(const int* __restrict__ row_ptr,
                                              const int* __restrict__ col,
                                              const float* __restrict__ z,
                                              const float* __restrict__ dinv,
                                              const float* __restrict__ b2,
                                              const float* __restrict__ Wl,
                                              const float* __restrict__ bl,
                                              float* __restrict__ out, int n) {
    int lane = threadIdx.x & 63;
    float c0 = b2[lane] * Wl[lane];
#pragma unroll
    for (int o = 32; o > 0; o >>= 1) c0 += __shfl_xor(c0, o, 64);
    c0 += bl[0];

    int tid = blockIdx.x * blockDim.x + threadIdx.x;
    int st  = gridDim.x * blockDim.x;
    for (int node = tid; node < n; node += st) {
        int beg = row_ptr[node];
        int end = row_ptr[node + 1];
        float s = z[node];
        int e = beg;
        for (; e + 4 <= end; e += 4) {
            float t0 = z[col[e]];
            float t1 = z[col[e + 1]];
            float t2 = z[col[e + 2]];
            float t3 = z[col[e + 3]];
            s += t0; s += t1; s += t2; s += t3;
        }
        for (; e < end; ++e) s += z[col[e]];
        float v = dinv[node] * s + c0;
        out[node] = 1.0f / (1.0f + expf(-v));
    }
}

// ---- launch ---------------------------------------------------------------

extern "C" void kernel_launch(void* const* d_in, const int* in_sizes, int n_in,
                              void* d_out, int out_size, void* d_ws, size_t ws_size,
                              hipStream_t stream) {
    const float* x   = (const float*)d_in[0];
    const int*   ei  = (const int*)d_in[1];   // [2, E] row-major
    const float* W1  = (const float*)d_in[2];
    const float* b1  = (const float*)d_in[3];
    const float* W2  = (const float*)d_in[4];
    const float* b2  = (const float*)d_in[5];
    const float* Wl  = (const float*)d_in[6];
    const float* bl  = (const float*)d_in[7];
    float*       out = (float*)d_out;

    const int N = in_sizes[0] / CH;
    const int E = in_sizes[1] / 2;
    const int* src = ei;
    const int* dst = ei + E;

    const size_t Npad = ((size_t)N + 511) & ~(size_t)511;
    const size_t Epad = ((size_t)E + 511) & ~(size_t)511;

    __half* A      = (__half*)d_ws;                   // N*CH halves (hs1, fp16)
    float* z       = (float*)(A + (size_t)N * CH);    // N
    float* dinv    = z + Npad;                        // N
    int*   row_ptr = (int*)(dinv + Npad);             // N+1
    int*   col     = row_ptr + Npad;                  // E
    unsigned int* ebuf = (unsigned int*)(col + Epad); // E
    int*   blkhist = (int*)(ebuf + Epad);             // NBLK_P*NBUCK
    int*   off_t   = blkhist + NBLK_P * NBUCK;        // NBUCK*NBLK_P (transposed)
    int*   bbase   = off_t + NBLK_P * NBUCK;          // NBUCK+1
    int*   tot     = bbase + NBUCK + 64;              // NBUCK

    const int TB = 256;
    const int GRID = 2048;
    const int NB_USED = (N + BMASK) >> BSHIFT;

    // CSR build — scatter-free, no single-block serial stages
    k_hist<<<NBLK_P, TB, 0, stream>>>(dst, blkhist, E);
    k_bucketscan<<<NBUCK * 64 / TB, TB, 0, stream>>>(blkhist, off_t, tot);
    k_scantot<<<1, NBUCK, 0, stream>>>(tot, bbase, row_ptr, N);
    k_partition<<<NBLK_P, TB, 0, stream>>>(src, dst, off_t, bbase, ebuf, E);
    k_bucket_csr<<<NB_USED, 128, 0, stream>>>(ebuf, bbase, row_ptr, dinv, col, N);

    // Layer 1: A = (x @ W1) * dinv  (fp16)
    k_gemm64<<<GRID, TB, 0, stream>>>(x, W1, dinv, A, N);

    // Layer 2 fused: gather(A) -> relu(agg1+b1) @ W2 * dinv -> dot(Wl) -> z
    k_gather_gemm<<<GRID, TB, 0, stream>>>(row_ptr, col, (const __half2*)A, dinv,
                                           W2, b1, Wl, z, N);

    // Head: scalar gather over z + sigmoid
    k_head<<<(N + TB - 1) / TB, TB, 0, stream>>>(row_ptr, col, z, dinv, b2, Wl, bl, out, N);
}